// Round 1
// 266.728 us; speedup vs baseline: 1.3086x; 1.3086x over previous
//
#include <hip/hip_runtime.h>
#include <math.h>
#include <float.h>

#define NEG_SLOPE 0.2f
#define NCHUNK 128   // edge-array chunks for the deterministic scatter

typedef _Float16 half8 __attribute__((ext_vector_type(8)));
typedef float f32x4  __attribute__((ext_vector_type(4)));

// K1: h = x @ W_gat (N x 11 @ 11 x 64) fp32 compute, fp16 store; a_src/a_dst fp32.
// Blocks 0-7 prep fp16 hi/lo weight fragments; block 8 zeroes sentinel rows.
__global__ __launch_bounds__(256) void gat_input_kernel(
    const float* __restrict__ x, const float* __restrict__ Wg,
    const float* __restrict__ att_src, const float* __restrict__ att_dst,
    _Float16* __restrict__ Hf, float* __restrict__ a_src, float* __restrict__ a_dst, int N,
    const float* __restrict__ W1l, const float* __restrict__ W1r,
    const float* __restrict__ W2l, const float* __restrict__ W2r,
    _Float16* __restrict__ W1hi, _Float16* __restrict__ W1lo,
    _Float16* __restrict__ W2hi, _Float16* __restrict__ W2lo,
    const float* __restrict__ alpha, float* __restrict__ wsm,
    _Float16* __restrict__ Psent)
{
    if (blockIdx.x < 8) {
        if (blockIdx.x == 0 && threadIdx.x == 0) {
            float m = alpha[0];
            for (int i = 1; i < 4; i++) m = fmaxf(m, alpha[i]);
            float e[4], s = 0.f;
            for (int i = 0; i < 4; i++) { e[i] = expf(alpha[i] - m); s += e[i]; }
            for (int i = 0; i < 4; i++) wsm[i] = e[i] / s;
        }
        int which = blockIdx.x >> 2;
        const float* Wl = which ? W2l : W1l;
        const float* Wr = which ? W2r : W1r;
        _Float16* Whi = which ? W2hi : W1hi;
        _Float16* Wlo = which ? W2lo : W1lo;
        int idx = (blockIdx.x & 3) * 256 + threadIdx.x;
        int kc = idx >> 9, rem = idx & 511;
        int t = rem >> 6, ln = rem & 63;
        int quad = ln >> 4, col16 = ln & 15;
        int c = t * 16 + col16;
        #pragma unroll
        for (int j = 0; j < 8; j++) {
            int k = kc * 32 + quad * 8 + j;
            float w = (c < 64) ? Wl[k * 64 + c] : Wr[k * 64 + (c - 64)];
            _Float16 hi = (_Float16)w;
            _Float16 lo = (_Float16)(w - (float)hi);
            Whi[(size_t)idx * 8 + j] = hi;
            Wlo[(size_t)idx * 8 + j] = lo;
        }
    } else if (blockIdx.x == 8) {
        if (threadIdx.x < 64) Hf[(size_t)N * 64 + threadIdx.x] = (_Float16)0.f;
        else if (threadIdx.x < 128) Psent[(size_t)N * 64 + (threadIdx.x - 64)] = (_Float16)0.f;
        else if (threadIdx.x == 128) a_src[N] = -1e30f;
    }
    __shared__ float Wl[11 * 64];
    int tid = threadIdx.x;
    for (int i = tid; i < 11 * 64; i += 256) Wl[i] = Wg[i];
    __syncthreads();
    int lane = tid & 63;
    int n = blockIdx.x * 4 + (tid >> 6);
    if (n >= N) return;
    float xv = (lane < 11) ? x[n * 11 + lane] : 0.f;
    float acc = 0.f;
    #pragma unroll
    for (int k = 0; k < 11; k++) acc += __shfl(xv, k, 64) * Wl[k * 64 + lane];
    Hf[(size_t)n * 64 + lane] = (_Float16)acc;
    float ps = acc * att_src[lane];
    float pd = acc * att_dst[lane];
    for (int off = 32; off; off >>= 1) {
        ps += __shfl_down(ps, off, 64);
        pd += __shfl_down(pd, off, 64);
    }
    if (lane == 0) { a_src[n] = ps; a_dst[n] = pd; }
}

// ---- Chunked CSR construction (bucket = dst >> 7; no global atomics) ----

__global__ __launch_bounds__(1024) void edge_hist_kernel(
    const int* __restrict__ dst, int* __restrict__ hist, int E, int NBK)
{
    __shared__ int c[1024];
    int t = threadIdx.x;
    c[t] = 0;
    __syncthreads();
    int chunk = (E + NCHUNK - 1) / NCHUNK;
    int lo = blockIdx.x * chunk;
    int hi = lo + chunk; if (hi > E) hi = E;
    for (int i = lo + t; i < hi; i += 1024)
        atomicAdd(&c[dst[i] >> 7], 1);
    __syncthreads();
    if (t < NBK) hist[t * NCHUNK + blockIdx.x] = c[t];
}

__global__ __launch_bounds__(1024) void edge_scatter_kernel(
    const int* __restrict__ src, const int* __restrict__ dst,
    const int* __restrict__ rstart, unsigned* __restrict__ ebuf, int E, int NBK)
{
    __shared__ int cur[1024];
    int t = threadIdx.x;
    if (t < NBK) cur[t] = rstart[t * NCHUNK + blockIdx.x];
    __syncthreads();
    int chunk = (E + NCHUNK - 1) / NCHUNK;
    int lo = blockIdx.x * chunk;
    int hi = lo + chunk; if (hi > E) hi = E;
    for (int i = lo + t; i < hi; i += 1024) {
        int d = dst[i];
        int p = atomicAdd(&cur[d >> 7], 1);
        ebuf[p] = ((unsigned)src[i] << 7) | (unsigned)(d & 127);
    }
}

// ---- exclusive scan: reduce + (spine folded into apply) ----
__global__ __launch_bounds__(256) void scan_reduce_kernel(
    const int* __restrict__ v, int* __restrict__ bsum, int M)
{
    __shared__ int s[256];
    int t = threadIdx.x;
    int base = blockIdx.x * 1024 + t * 4;
    int sum = 0;
    #pragma unroll
    for (int j = 0; j < 4; j++) { int idx = base + j; if (idx < M) sum += v[idx]; }
    s[t] = sum; __syncthreads();
    for (int off = 128; off; off >>= 1) {
        if (t < off) s[t] += s[t + off];
        __syncthreads();
    }
    if (t == 0) bsum[blockIdx.x] = s[0];
}

__global__ __launch_bounds__(256) void scan_apply_kernel(
    const int* __restrict__ v, const int* __restrict__ bsum,
    int* __restrict__ out, int M, int NB)
{
    __shared__ int s[256];
    int t = threadIdx.x;
    int bv = (t < NB) ? bsum[t] : 0;
    s[t] = bv; __syncthreads();
    for (int off = 1; off < 256; off <<= 1) {
        int xx = (t >= off) ? s[t - off] : 0;
        __syncthreads();
        s[t] += xx;
        __syncthreads();
    }
    int blockoff = (blockIdx.x == 0) ? 0 : s[blockIdx.x - 1];
    __syncthreads();
    int base = blockIdx.x * 1024;
    int vv[4]; int sum = 0;
    #pragma unroll
    for (int j = 0; j < 4; j++) {
        int idx = base + t * 4 + j;
        vv[j] = (idx < M) ? v[idx] : 0;
        sum += vv[j];
    }
    s[t] = sum; __syncthreads();
    for (int off = 1; off < 256; off <<= 1) {
        int xx = (t >= off) ? s[t - off] : 0;
        __syncthreads();
        s[t] += xx;
        __syncthreads();
    }
    int ex = s[t] - sum + blockoff;
    #pragma unroll
    for (int j = 0; j < 4; j++) {
        int idx = base + t * 4 + j;
        if (idx < M) out[idx] = ex;
        ex += vv[j];
    }
}

// one workgroup per bucket: LDS counts -> padded LDS scan -> cnt/rowstart -> csr (+pads)
__global__ __launch_bounds__(256) void bucket_build_kernel(
    const unsigned* __restrict__ ebuf, const int* __restrict__ rstart,
    int* __restrict__ cnt, int* __restrict__ rowstart,
    int* __restrict__ csr, int E, int N, int NBK)
{
    __shared__ int c[128];
    __shared__ int rs[128];
    __shared__ int cur[128];
    int b = blockIdx.x, t = threadIdx.x;
    if (t < 128) { c[t] = 0; cur[t] = 0; }
    __syncthreads();
    int beg = rstart[b * NCHUNK];
    int end = (b == NBK - 1) ? E : rstart[(b + 1) * NCHUNK];
    int n = end - beg;
    int pbeg = beg + 384 * b;
    for (int j = t; j < n; j += 256)
        atomicAdd(&c[ebuf[beg + j] & 127u], 1);
    __syncthreads();
    int myc = (t < 128) ? c[t] : 0;
    int mypc = (myc + 3) & ~3;
    if (t < 128) rs[t] = mypc;
    __syncthreads();
    for (int off = 1; off < 128; off <<= 1) {
        int v = (t < 128 && t >= off) ? rs[t - off] : 0;
        __syncthreads();
        if (t < 128) rs[t] += v;
        __syncthreads();
    }
    int ex = (t < 128) ? (rs[t] - mypc) : 0;
    __syncthreads();
    if (t < 128) rs[t] = ex;
    int base = b << 7;
    if (t < 128 && base + t < N) {
        cnt[base + t] = myc;
        rowstart[base + t] = pbeg + ex;
    }
    __syncthreads();
    for (int j = t; j < n; j += 256) {
        unsigned e = ebuf[beg + j];
        int d = (int)(e & 127u);
        int p = atomicAdd(&cur[d], 1);
        csr[pbeg + rs[d] + p] = (int)(e >> 7);
    }
    __syncthreads();
    if (t < 128) {
        for (int k = myc; k < mypc; k++) csr[pbeg + rs[t] + k] = N;
    }
}

// K2: GAT gather — 8 lanes per dst node (16B fp16 loads), 8-deep batches.
__global__ __launch_bounds__(256) void gat_gather_kernel(
    const _Float16* __restrict__ Hf, const float* __restrict__ a_src,
    const float* __restrict__ a_dst, const float* __restrict__ bg,
    const int* __restrict__ rowstart, const int* __restrict__ cnt,
    const int* __restrict__ csr, const float* __restrict__ wsm,
    _Float16* __restrict__ HG, _Float16* __restrict__ outD, int N)
{
    const half8* __restrict__ H8 = (const half8*)Hf;
    int tid = threadIdx.x;
    int lane = tid & 63;
    int g = lane >> 3, sub = lane & 7;
    int gl = g << 3;
    int d = blockIdx.x * 32 + (tid >> 3);
    if (d >= N) return;
    float ad = a_dst[d];
    int beg = rowstart[d], deg = cnt[d];
    int degp = (deg + 3) & ~3;
    float a0 = a_src[d] + ad;
    float lg0 = a0 > 0.f ? a0 : NEG_SLOPE * a0;
    float w_self = expf(lg0);
    half8 hself = H8[(size_t)d * 8 + sub];
    float acc[8];
    #pragma unroll
    for (int c = 0; c < 8; c++) acc[c] = w_self * (float)hself[c];
    float l_lane = 0.f;
    for (int base = 0; base < degp; base += 8) {
        int nvc = degp - base; if (nvc > 8) nvc = 8;
        int sid = (sub < nvc) ? csr[beg + base + sub] : N;
        float aa = a_src[sid] + ad;
        float lgt = aa > 0.f ? aa : NEG_SLOPE * aa;
        float w = expf(lgt);
        l_lane += w;
        int ib[8]; float wb[8];
        #pragma unroll
        for (int j = 0; j < 8; j++) {
            ib[j] = __shfl(sid, gl + j, 64);
            wb[j] = __shfl(w, gl + j, 64);
        }
        half8 v[8];
        #pragma unroll
        for (int j = 0; j < 8; j++) v[j] = H8[(size_t)ib[j] * 8 + sub];
        #pragma unroll
        for (int j = 0; j < 8; j++) {
            #pragma unroll
            for (int c = 0; c < 8; c++) acc[c] += wb[j] * (float)v[j][c];
        }
    }
    #pragma unroll
    for (int off = 1; off < 8; off <<= 1) l_lane += __shfl_xor(l_lane, off, 64);
    float l = l_lane + w_self;
    float inv = 1.0f / (l + 1e-16f);
    float w0s = wsm[0];
    size_t idx = (size_t)d * 8 + sub;
    half8 hg, od;
    #pragma unroll
    for (int c = 0; c < 8; c++) {
        float o = acc[c] * inv + bg[sub * 8 + c];
        hg[c] = (_Float16)o;
        od[c] = (_Float16)(w0s * o);
    }
    ((half8*)HG)[idx] = hg;
    ((half8*)outD)[idx] = od;
}

// K6: dense GEMM [P|Q] = hin @ [Wl|Wr] (+b on Q half) via mfma 16x16x32 f16 x2 (hi/lo weights).
__global__ __launch_bounds__(256) void sage_gemm_kernel(
    const _Float16* __restrict__ hin,
    const _Float16* __restrict__ Whi, const _Float16* __restrict__ Wlo,
    const float* __restrict__ bvec,
    _Float16* __restrict__ P, _Float16* __restrict__ Q, int N)
{
    int wave = threadIdx.x >> 6, lane = threadIdx.x & 63;
    int base = blockIdx.x * 64 + wave * 16;
    if (base >= N) return;
    int quad = lane >> 4, col16 = lane & 15;
    int m = base + col16;
    int mc = m < N ? m : N - 1;
    const half8* __restrict__ W8hi = (const half8*)Whi;
    const half8* __restrict__ W8lo = (const half8*)Wlo;
    f32x4 acc[8];
    #pragma unroll
    for (int t = 0; t < 8; t++) acc[t] = (f32x4){0.f, 0.f, 0.f, 0.f};
    #pragma unroll
    for (int kc = 0; kc < 2; kc++) {
        half8 a = *(const half8*)(hin + (size_t)mc * 64 + kc * 32 + quad * 8);
        #pragma unroll
        for (int t = 0; t < 8; t++) {
            size_t off = (size_t)(kc * 8 + t) * 64 + lane;
            half8 bhi = W8hi[off];
            half8 blo = W8lo[off];
            acc[t] = __builtin_amdgcn_mfma_f32_16x16x32_f16(a, bhi, acc[t], 0, 0, 0);
            acc[t] = __builtin_amdgcn_mfma_f32_16x16x32_f16(a, blo, acc[t], 0, 0, 0);
        }
    }
    #pragma unroll
    for (int t = 0; t < 8; t++) {
        #pragma unroll
        for (int r = 0; r < 4; r++) {
            int node = base + quad * 4 + r;
            if (node < N) {
                float v = acc[t][r];
                if (t < 4) {
                    P[(size_t)node * 64 + t * 16 + col16] = (_Float16)v;
                } else {
                    int c = (t - 4) * 16 + col16;
                    Q[(size_t)node * 64 + c] = (_Float16)(v + bvec[c]);
                }
            }
        }
    }
}

// K7: SAGE post — 8 lanes per dst node (16B fp16 loads), 8-deep batches.
__global__ __launch_bounds__(256) void sage_post_kernel(
    const _Float16* __restrict__ P, const _Float16* __restrict__ Q,
    const int* __restrict__ rowstart, const int* __restrict__ cnt,
    const int* __restrict__ csr, const float* __restrict__ wsm, int widx,
    _Float16* __restrict__ hout, _Float16* __restrict__ outD, int N)
{
    const half8* __restrict__ P8 = (const half8*)P;
    int tid = threadIdx.x;
    int lane = tid & 63;
    int g = lane >> 3, sub = lane & 7;
    int gl = g << 3;
    int d = blockIdx.x * 32 + (tid >> 3);
    if (d >= N) return;
    int beg = rowstart[d], deg = cnt[d];
    int degp = (deg + 3) & ~3;
    float acc[8];
    #pragma unroll
    for (int c = 0; c < 8; c++) acc[c] = 0.f;
    for (int base = 0; base < degp; base += 8) {
        int nvc = degp - base; if (nvc > 8) nvc = 8;
        int sid = (sub < nvc) ? csr[beg + base + sub] : N;
        int ib[8];
        #pragma unroll
        for (int j = 0; j < 8; j++) ib[j] = __shfl(sid, gl + j, 64);
        half8 v[8];
        #pragma unroll
        for (int j = 0; j < 8; j++) v[j] = P8[(size_t)ib[j] * 8 + sub];
        #pragma unroll
        for (int j = 0; j < 8; j++) {
            #pragma unroll
            for (int c = 0; c < 8; c++) acc[c] += (float)v[j][c];
        }
    }
    float invd = 1.0f / fmaxf((float)deg, 1.0f);
    size_t idx = (size_t)d * 8 + sub;
    half8 q = ((const half8*)Q)[idx];
    half8 od = ((half8*)outD)[idx];
    float w = wsm[widx];
    half8 ho;
    #pragma unroll
    for (int c = 0; c < 8; c++) {
        float o = acc[c] * invd + (float)q[c];
        ho[c] = (_Float16)o;
        od[c] = (_Float16)((float)od[c] + w * o);
    }
    if (hout) ((half8*)hout)[idx] = ho;
    ((half8*)outD)[idx] = od;
}

// K8: 8 lanes per label-edge (fp16 rows): out[e] = dot(outf[a], outf[b])
__global__ __launch_bounds__(256) void link_pred_kernel(
    const int* __restrict__ eli, const _Float16* __restrict__ outf,
    float* __restrict__ out, int EL)
{
    const half8* __restrict__ o8 = (const half8*)outf;
    int e = blockIdx.x * 32 + (threadIdx.x >> 3);
    int sub = threadIdx.x & 7;
    if (e >= EL) return;
    int a = eli[e], b = eli[EL + e];
    half8 pa = o8[(size_t)a * 8 + sub];
    half8 pb = o8[(size_t)b * 8 + sub];
    float p = 0.f;
    #pragma unroll
    for (int c = 0; c < 8; c++) p += (float)pa[c] * (float)pb[c];
    for (int off = 4; off; off >>= 1) p += __shfl_xor(p, off, 64);
    if (sub == 0) out[e] = p;
}

extern "C" void kernel_launch(void* const* d_in, const int* in_sizes, int n_in,
                              void* d_out, int out_size, void* d_ws, size_t ws_size,
                              hipStream_t stream)
{
    const float* x      = (const float*)d_in[0];
    const int*   ei     = (const int*)d_in[1];
    const int*   eli    = (const int*)d_in[2];
    const float* Wg     = (const float*)d_in[3];
    const float* att_s  = (const float*)d_in[4];
    const float* att_d  = (const float*)d_in[5];
    const float* bg     = (const float*)d_in[6];
    const float* W1l    = (const float*)d_in[7];
    const float* W1r    = (const float*)d_in[8];
    const float* b1     = (const float*)d_in[9];
    const float* W2l    = (const float*)d_in[10];
    const float* W2r    = (const float*)d_in[11];
    const float* b2     = (const float*)d_in[12];
    const float* alpha  = (const float*)d_in[13];

    const int N  = in_sizes[0] / 11;
    const int E  = in_sizes[1] / 2;
    const int EL = in_sizes[2] / 2;
    const int NBK = (N + 127) >> 7;
    const int M   = NBK * NCHUNK;
    const int CSRSZ = E + 384 * NBK;

    const int* src = ei;
    const int* dst = ei + E;

    // workspace layout: fp16 node tables first (16B-aligned), then fp32/int arrays.
    _Float16* Hf  = (_Float16*)d_ws;                   // (N+1)*64  (sentinel row N = 0)
    _Float16* HG  = Hf + (size_t)(N + 1) * 64;         // N*64  GAT output
    _Float16* H1  = HG + (size_t)N * 64;               // N*64  layer-1 output
    _Float16* Pt  = H1 + (size_t)N * 64;               // (N+1)*64 (sentinel row N = 0)
    _Float16* Qt  = Pt + (size_t)(N + 1) * 64;         // N*64
    _Float16* oD  = Qt + (size_t)N * 64;               // N*64  fp16 output accumulator
    _Float16* wf  = oD + (size_t)N * 64;               // 4 x 8192 weight fragments
    _Float16* W1hi = wf;
    _Float16* W1lo = wf + 8192;
    _Float16* W2hi = wf + 16384;
    _Float16* W2lo = wf + 24576;
    float* wsm     = (float*)(wf + 32768);             // 4
    float* a_src   = wsm + 4;                          // N+1
    float* a_dst   = a_src + (N + 1);                  // N
    int*   cnt     = (int*)(a_dst + N);                // N
    int*   rowstart= cnt + N;                          // N
    int*   hist    = rowstart + N;                     // M
    int*   rstart  = hist + M;                         // M
    int*   bsum    = rstart + M;                       // 256
    int*   csr     = bsum + 256;                       // CSRSZ
    unsigned* ebuf = (unsigned*)Pt;                    // E uints, dead before GEMM#1

    gat_input_kernel<<<(N + 3) / 4, 256, 0, stream>>>(x, Wg, att_s, att_d, Hf, a_src, a_dst, N,
                                                      W1l, W1r, W2l, W2r,
                                                      W1hi, W1lo, W2hi, W2lo, alpha, wsm, Pt);

    edge_hist_kernel<<<NCHUNK, 1024, 0, stream>>>(dst, hist, E, NBK);
    int NB = (M + 1023) / 1024;
    scan_reduce_kernel<<<NB, 256, 0, stream>>>(hist, bsum, M);
    scan_apply_kernel<<<NB, 256, 0, stream>>>(hist, bsum, rstart, M, NB);
    edge_scatter_kernel<<<NCHUNK, 1024, 0, stream>>>(src, dst, rstart, ebuf, E, NBK);
    bucket_build_kernel<<<NBK, 256, 0, stream>>>(ebuf, rstart, cnt, rowstart, csr, E, N, NBK);

    gat_gather_kernel<<<(N + 31) / 32, 256, 0, stream>>>(Hf, a_src, a_dst, bg,
                                                         rowstart, cnt, csr, wsm, HG, oD, N);

    sage_gemm_kernel<<<(N + 63) / 64, 256, 0, stream>>>(HG, W1hi, W1lo, b1, Pt, Qt, N);
    sage_post_kernel<<<(N + 31) / 32, 256, 0, stream>>>(Pt, Qt, rowstart, cnt, csr, wsm, 2, H1, oD, N);

    sage_gemm_kernel<<<(N + 63) / 64, 256, 0, stream>>>(H1, W1hi == W1hi ? W2hi : W2hi, W2lo, b2, Pt, Qt, N);
    sage_post_kernel<<<(N + 31) / 32, 256, 0, stream>>>(Pt, Qt, rowstart, cnt, csr, wsm, 3, nullptr, oD, N);

    link_pred_kernel<<<(EL + 31) / 32, 256, 0, stream>>>(eli, oD, (float*)d_out, EL);
}

// Round 2
// 248.128 us; speedup vs baseline: 1.4067x; 1.0750x over previous
//
#include <hip/hip_runtime.h>
#include <math.h>
#include <float.h>

#define NEG_SLOPE 0.2f
#define NCHUNK 128   // edge-array chunks for the deterministic scatter

typedef _Float16 half8 __attribute__((ext_vector_type(8)));
typedef float f32x4  __attribute__((ext_vector_type(4)));

// K1: h = x @ W_gat (N x 11 @ 11 x 64) fp32 compute, fp16 store; a_src/a_dst fp32.
// Blocks 0-7 prep fp16 hi/lo weight fragments (K=128 concat layout for the fused
// SAGE kernel); block 8 zeroes sentinel rows of Hf/HG/H1 and sets a_src[N].
__global__ __launch_bounds__(256) void gat_input_kernel(
    const float* __restrict__ x, const float* __restrict__ Wg,
    const float* __restrict__ att_src, const float* __restrict__ att_dst,
    _Float16* __restrict__ Hf, float* __restrict__ a_src, float* __restrict__ a_dst, int N,
    const float* __restrict__ W1l, const float* __restrict__ W1r,
    const float* __restrict__ W2l, const float* __restrict__ W2r,
    _Float16* __restrict__ W1hi, _Float16* __restrict__ W1lo,
    _Float16* __restrict__ W2hi, _Float16* __restrict__ W2lo,
    const float* __restrict__ alpha, float* __restrict__ wsm,
    _Float16* __restrict__ HG, _Float16* __restrict__ H1)
{
    if (blockIdx.x < 8) {
        if (blockIdx.x == 0 && threadIdx.x == 0) {
            float m = alpha[0];
            for (int i = 1; i < 4; i++) m = fmaxf(m, alpha[i]);
            float e[4], s = 0.f;
            for (int i = 0; i < 4; i++) { e[i] = expf(alpha[i] - m); s += e[i]; }
            for (int i = 0; i < 4; i++) wsm[i] = e[i] / s;
        }
        int which = blockIdx.x >> 2;
        const float* Wl = which ? W2l : W1l;
        const float* Wr = which ? W2r : W1r;
        _Float16* Whi = which ? W2hi : W1hi;
        _Float16* Wlo = which ? W2lo : W1lo;
        // B-fragment layout for out = [agg|self] @ [Wl;Wr]: K=128, 64 outputs.
        // linear idx = (kc*4 + t)*64 + lane;  k = kc*32 + quad*8 + j;  c = t*16 + col16.
        int idx = (blockIdx.x & 3) * 256 + threadIdx.x;
        int kc = idx >> 8, rem = idx & 255;
        int t = rem >> 6, ln = rem & 63;
        int quad = ln >> 4, col16 = ln & 15;
        int c = t * 16 + col16;
        #pragma unroll
        for (int j = 0; j < 8; j++) {
            int k = kc * 32 + quad * 8 + j;
            float w = (k < 64) ? Wl[k * 64 + c] : Wr[(k - 64) * 64 + c];
            _Float16 hi = (_Float16)w;
            _Float16 lo = (_Float16)(w - (float)hi);
            Whi[(size_t)idx * 8 + j] = hi;
            Wlo[(size_t)idx * 8 + j] = lo;
        }
    } else if (blockIdx.x == 8) {
        if (threadIdx.x < 64) Hf[(size_t)N * 64 + threadIdx.x] = (_Float16)0.f;
        else if (threadIdx.x < 128) HG[(size_t)N * 64 + (threadIdx.x - 64)] = (_Float16)0.f;
        else if (threadIdx.x < 192) H1[(size_t)N * 64 + (threadIdx.x - 128)] = (_Float16)0.f;
        else if (threadIdx.x == 192) a_src[N] = -1e30f;
    }
    __shared__ float Wl[11 * 64];
    int tid = threadIdx.x;
    for (int i = tid; i < 11 * 64; i += 256) Wl[i] = Wg[i];
    __syncthreads();
    int lane = tid & 63;
    int n = blockIdx.x * 4 + (tid >> 6);
    if (n >= N) return;
    float xv = (lane < 11) ? x[n * 11 + lane] : 0.f;
    float acc = 0.f;
    #pragma unroll
    for (int k = 0; k < 11; k++) acc += __shfl(xv, k, 64) * Wl[k * 64 + lane];
    Hf[(size_t)n * 64 + lane] = (_Float16)acc;
    float ps = acc * att_src[lane];
    float pd = acc * att_dst[lane];
    for (int off = 32; off; off >>= 1) {
        ps += __shfl_down(ps, off, 64);
        pd += __shfl_down(pd, off, 64);
    }
    if (lane == 0) { a_src[n] = ps; a_dst[n] = pd; }
}

// ---- Chunked CSR construction (bucket = dst >> 7; no global atomics) ----

__global__ __launch_bounds__(1024) void edge_hist_kernel(
    const int* __restrict__ dst, int* __restrict__ hist, int E, int NBK)
{
    __shared__ int c[1024];
    int t = threadIdx.x;
    c[t] = 0;
    __syncthreads();
    int chunk = (E + NCHUNK - 1) / NCHUNK;
    int lo = blockIdx.x * chunk;
    int hi = lo + chunk; if (hi > E) hi = E;
    for (int i = lo + t; i < hi; i += 1024)
        atomicAdd(&c[dst[i] >> 7], 1);
    __syncthreads();
    if (t < NBK) hist[t * NCHUNK + blockIdx.x] = c[t];
}

__global__ __launch_bounds__(1024) void edge_scatter_kernel(
    const int* __restrict__ src, const int* __restrict__ dst,
    const int* __restrict__ rstart, unsigned* __restrict__ ebuf, int E, int NBK)
{
    __shared__ int cur[1024];
    int t = threadIdx.x;
    if (t < NBK) cur[t] = rstart[t * NCHUNK + blockIdx.x];
    __syncthreads();
    int chunk = (E + NCHUNK - 1) / NCHUNK;
    int lo = blockIdx.x * chunk;
    int hi = lo + chunk; if (hi > E) hi = E;
    for (int i = lo + t; i < hi; i += 1024) {
        int d = dst[i];
        int p = atomicAdd(&cur[d >> 7], 1);
        ebuf[p] = ((unsigned)src[i] << 7) | (unsigned)(d & 127);
    }
}

// ---- exclusive scan: reduce + (spine folded into apply) ----
__global__ __launch_bounds__(256) void scan_reduce_kernel(
    const int* __restrict__ v, int* __restrict__ bsum, int M)
{
    __shared__ int s[256];
    int t = threadIdx.x;
    int base = blockIdx.x * 1024 + t * 4;
    int sum = 0;
    #pragma unroll
    for (int j = 0; j < 4; j++) { int idx = base + j; if (idx < M) sum += v[idx]; }
    s[t] = sum; __syncthreads();
    for (int off = 128; off; off >>= 1) {
        if (t < off) s[t] += s[t + off];
        __syncthreads();
    }
    if (t == 0) bsum[blockIdx.x] = s[0];
}

__global__ __launch_bounds__(256) void scan_apply_kernel(
    const int* __restrict__ v, const int* __restrict__ bsum,
    int* __restrict__ out, int M, int NB)
{
    __shared__ int s[256];
    int t = threadIdx.x;
    int bv = (t < NB) ? bsum[t] : 0;
    s[t] = bv; __syncthreads();
    for (int off = 1; off < 256; off <<= 1) {
        int xx = (t >= off) ? s[t - off] : 0;
        __syncthreads();
        s[t] += xx;
        __syncthreads();
    }
    int blockoff = (blockIdx.x == 0) ? 0 : s[blockIdx.x - 1];
    __syncthreads();
    int base = blockIdx.x * 1024;
    int vv[4]; int sum = 0;
    #pragma unroll
    for (int j = 0; j < 4; j++) {
        int idx = base + t * 4 + j;
        vv[j] = (idx < M) ? v[idx] : 0;
        sum += vv[j];
    }
    s[t] = sum; __syncthreads();
    for (int off = 1; off < 256; off <<= 1) {
        int xx = (t >= off) ? s[t - off] : 0;
        __syncthreads();
        s[t] += xx;
        __syncthreads();
    }
    int ex = s[t] - sum + blockoff;
    #pragma unroll
    for (int j = 0; j < 4; j++) {
        int idx = base + t * 4 + j;
        if (idx < M) out[idx] = ex;
        ex += vv[j];
    }
}

// one workgroup per bucket: LDS counts -> padded LDS scan -> cnt/rowstart -> csr (+pads)
__global__ __launch_bounds__(256) void bucket_build_kernel(
    const unsigned* __restrict__ ebuf, const int* __restrict__ rstart,
    int* __restrict__ cnt, int* __restrict__ rowstart,
    int* __restrict__ csr, int E, int N, int NBK)
{
    __shared__ int c[128];
    __shared__ int rs[128];
    __shared__ int cur[128];
    int b = blockIdx.x, t = threadIdx.x;
    if (t < 128) { c[t] = 0; cur[t] = 0; }
    __syncthreads();
    int beg = rstart[b * NCHUNK];
    int end = (b == NBK - 1) ? E : rstart[(b + 1) * NCHUNK];
    int n = end - beg;
    int pbeg = beg + 384 * b;
    for (int j = t; j < n; j += 256)
        atomicAdd(&c[ebuf[beg + j] & 127u], 1);
    __syncthreads();
    int myc = (t < 128) ? c[t] : 0;
    int mypc = (myc + 3) & ~3;
    if (t < 128) rs[t] = mypc;
    __syncthreads();
    for (int off = 1; off < 128; off <<= 1) {
        int v = (t < 128 && t >= off) ? rs[t - off] : 0;
        __syncthreads();
        if (t < 128) rs[t] += v;
        __syncthreads();
    }
    int ex = (t < 128) ? (rs[t] - mypc) : 0;
    __syncthreads();
    if (t < 128) rs[t] = ex;
    int base = b << 7;
    if (t < 128 && base + t < N) {
        cnt[base + t] = myc;
        rowstart[base + t] = pbeg + ex;
    }
    __syncthreads();
    for (int j = t; j < n; j += 256) {
        unsigned e = ebuf[beg + j];
        int d = (int)(e & 127u);
        int p = atomicAdd(&cur[d], 1);
        csr[pbeg + rs[d] + p] = (int)(e >> 7);
    }
    __syncthreads();
    if (t < 128) {
        for (int k = myc; k < mypc; k++) csr[pbeg + rs[t] + k] = N;
    }
}

// K2: GAT gather — 8 lanes per dst node (16B fp16 loads), 8-deep batches.
__global__ __launch_bounds__(256) void gat_gather_kernel(
    const _Float16* __restrict__ Hf, const float* __restrict__ a_src,
    const float* __restrict__ a_dst, const float* __restrict__ bg,
    const int* __restrict__ rowstart, const int* __restrict__ cnt,
    const int* __restrict__ csr, const float* __restrict__ wsm,
    _Float16* __restrict__ HG, _Float16* __restrict__ outD, int N)
{
    const half8* __restrict__ H8 = (const half8*)Hf;
    int tid = threadIdx.x;
    int lane = tid & 63;
    int g = lane >> 3, sub = lane & 7;
    int gl = g << 3;
    int d = blockIdx.x * 32 + (tid >> 3);
    if (d >= N) return;
    float ad = a_dst[d];
    int beg = rowstart[d], deg = cnt[d];
    int degp = (deg + 3) & ~3;
    float a0 = a_src[d] + ad;
    float lg0 = a0 > 0.f ? a0 : NEG_SLOPE * a0;
    float w_self = expf(lg0);
    half8 hself = H8[(size_t)d * 8 + sub];
    float acc[8];
    #pragma unroll
    for (int c = 0; c < 8; c++) acc[c] = w_self * (float)hself[c];
    float l_lane = 0.f;
    for (int base = 0; base < degp; base += 8) {
        int nvc = degp - base; if (nvc > 8) nvc = 8;
        int sid = (sub < nvc) ? csr[beg + base + sub] : N;
        float aa = a_src[sid] + ad;
        float lgt = aa > 0.f ? aa : NEG_SLOPE * aa;
        float w = expf(lgt);
        l_lane += w;
        int ib[8]; float wb[8];
        #pragma unroll
        for (int j = 0; j < 8; j++) {
            ib[j] = __shfl(sid, gl + j, 64);
            wb[j] = __shfl(w, gl + j, 64);
        }
        half8 v[8];
        #pragma unroll
        for (int j = 0; j < 8; j++) v[j] = H8[(size_t)ib[j] * 8 + sub];
        #pragma unroll
        for (int j = 0; j < 8; j++) {
            #pragma unroll
            for (int c = 0; c < 8; c++) acc[c] += wb[j] * (float)v[j][c];
        }
    }
    #pragma unroll
    for (int off = 1; off < 8; off <<= 1) l_lane += __shfl_xor(l_lane, off, 64);
    float l = l_lane + w_self;
    float inv = 1.0f / (l + 1e-16f);
    float w0s = wsm[0];
    size_t idx = (size_t)d * 8 + sub;
    half8 hg, od;
    #pragma unroll
    for (int c = 0; c < 8; c++) {
        float o = acc[c] * inv + bg[sub * 8 + c];
        hg[c] = (_Float16)o;
        od[c] = (_Float16)(w0s * o);
    }
    ((half8*)HG)[idx] = hg;
    ((half8*)outD)[idx] = od;
}

// K5: fused SAGE layer: out = mean_agg(neigh(Hin)) @ Wl + Hin @ Wr + b,
// computed as [agg | self] (K=128) @ [Wl;Wr] via mfma 16x16x32 f16 (W hi/lo).
// Per block: 64 nodes. Phase 1: gather mean into XOR-swizzled LDS A-tile.
// Phase 2: 4 waves x 16 rows MFMA. Phase 3: coalesced half8 epilogue via LDS.
__global__ __launch_bounds__(256) void sage_fused_kernel(
    const _Float16* __restrict__ Hin,
    const _Float16* __restrict__ Whi, const _Float16* __restrict__ Wlo,
    const float* __restrict__ bvec,
    const int* __restrict__ rowstart, const int* __restrict__ cnt,
    const int* __restrict__ csr, const float* __restrict__ wsm, int widx,
    _Float16* __restrict__ hout, _Float16* __restrict__ outD, int N)
{
    // A-tile: 64 rows x 128 halves (256B), XOR-swizzled 16B slots. 16384 B.
    // Out-tile (aliased, used after barrier): 64 rows x 68 floats. 17408 B.
    __shared__ __align__(16) char smem[64 * 68 * 4];
    float* Ot = (float*)smem;
    const half8* __restrict__ H8 = (const half8*)Hin;
    int tid = threadIdx.x;
    int lane = tid & 63;
    int nodeBase = blockIdx.x * 64;
    int sub = tid & 7;
    int g = lane >> 3;
    int gl = g << 3;

    // ---- phase 1: gather mean-agg, 2 passes x 32 nodes, 8 lanes/node ----
    #pragma unroll
    for (int pass = 0; pass < 2; pass++) {
        int dloc = pass * 32 + (tid >> 3);
        int d = nodeBase + dloc;
        float acc[8];
        #pragma unroll
        for (int c = 0; c < 8; c++) acc[c] = 0.f;
        half8 hself;
        #pragma unroll
        for (int c = 0; c < 8; c++) hself[c] = (_Float16)0.f;
        float invd = 0.f;
        if (d < N) {
            int beg = rowstart[d], deg = cnt[d];
            int degp = (deg + 3) & ~3;
            for (int base2 = 0; base2 < degp; base2 += 8) {
                int nvc = degp - base2; if (nvc > 8) nvc = 8;
                int sid = (sub < nvc) ? csr[beg + base2 + sub] : N;
                int ib[8];
                #pragma unroll
                for (int j = 0; j < 8; j++) ib[j] = __shfl(sid, gl + j, 64);
                half8 v[8];
                #pragma unroll
                for (int j = 0; j < 8; j++) v[j] = H8[(size_t)ib[j] * 8 + sub];
                #pragma unroll
                for (int j = 0; j < 8; j++) {
                    #pragma unroll
                    for (int c = 0; c < 8; c++) acc[c] += (float)v[j][c];
                }
            }
            invd = 1.0f / fmaxf((float)deg, 1.0f);
            hself = H8[(size_t)d * 8 + sub];
        }
        half8 ah;
        #pragma unroll
        for (int c = 0; c < 8; c++) ah[c] = (_Float16)(acc[c] * invd);
        int rbase = dloc * 256;
        int swz = (dloc & 7) << 4;
        *(half8*)(smem + ((rbase + sub * 16) ^ swz)) = ah;          // k = sub*8..+8
        *(half8*)(smem + ((rbase + 128 + sub * 16) ^ swz)) = hself; // k = 64+sub*8..+8
    }
    __syncthreads();

    // ---- phase 2: MFMA, 4 waves x 16 rows, K=128 ----
    int quad = lane >> 4, col16 = lane & 15;
    int wave = tid >> 6;
    int row = wave * 16 + col16;
    int rswz = (row & 7) << 4;
    f32x4 accq[4];
    #pragma unroll
    for (int t = 0; t < 4; t++) accq[t] = (f32x4){0.f, 0.f, 0.f, 0.f};
    #pragma unroll
    for (int kc = 0; kc < 4; kc++) {
        half8 a = *(const half8*)(smem + ((row * 256 + kc * 64 + quad * 16) ^ rswz));
        #pragma unroll
        for (int t = 0; t < 4; t++) {
            size_t off = (size_t)((kc * 4 + t) * 64 + lane) * 8;
            half8 bhi = *(const half8*)(Whi + off);
            half8 blo = *(const half8*)(Wlo + off);
            accq[t] = __builtin_amdgcn_mfma_f32_16x16x32_f16(a, bhi, accq[t], 0, 0, 0);
            accq[t] = __builtin_amdgcn_mfma_f32_16x16x32_f16(a, blo, accq[t], 0, 0, 0);
        }
    }
    __syncthreads();   // all A-tile reads done before Ot overwrites (aliased)
    #pragma unroll
    for (int t = 0; t < 4; t++) {
        #pragma unroll
        for (int r = 0; r < 4; r++) {
            Ot[(wave * 16 + quad * 4 + r) * 68 + t * 16 + col16] = accq[t][r];
        }
    }
    __syncthreads();

    // ---- phase 3: epilogue, 2 passes x 32 nodes, 8 lanes/node ----
    float w = wsm[widx];
    #pragma unroll
    for (int pass = 0; pass < 2; pass++) {
        int dloc = pass * 32 + (tid >> 3);
        int d = nodeBase + dloc;
        if (d >= N) continue;
        size_t idx = (size_t)d * 8 + sub;
        float4 o0 = *(float4*)&Ot[dloc * 68 + sub * 8];
        float4 o1 = *(float4*)&Ot[dloc * 68 + sub * 8 + 4];
        float4 b0 = *(const float4*)&bvec[sub * 8];
        float4 b1 = *(const float4*)&bvec[sub * 8 + 4];
        float o[8] = {o0.x + b0.x, o0.y + b0.y, o0.z + b0.z, o0.w + b0.w,
                      o1.x + b1.x, o1.y + b1.y, o1.z + b1.z, o1.w + b1.w};
        half8 od = ((half8*)outD)[idx];
        half8 ho;
        #pragma unroll
        for (int c = 0; c < 8; c++) {
            ho[c] = (_Float16)o[c];
            od[c] = (_Float16)((float)od[c] + w * o[c]);
        }
        if (hout) ((half8*)hout)[idx] = ho;
        ((half8*)outD)[idx] = od;
    }
}

// K8: 8 lanes per label-edge (fp16 rows): out[e] = dot(outf[a], outf[b])
__global__ __launch_bounds__(256) void link_pred_kernel(
    const int* __restrict__ eli, const _Float16* __restrict__ outf,
    float* __restrict__ out, int EL)
{
    const half8* __restrict__ o8 = (const half8*)outf;
    int e = blockIdx.x * 32 + (threadIdx.x >> 3);
    int sub = threadIdx.x & 7;
    if (e >= EL) return;
    int a = eli[e], b = eli[EL + e];
    half8 pa = o8[(size_t)a * 8 + sub];
    half8 pb = o8[(size_t)b * 8 + sub];
    float p = 0.f;
    #pragma unroll
    for (int c = 0; c < 8; c++) p += (float)pa[c] * (float)pb[c];
    for (int off = 4; off; off >>= 1) p += __shfl_xor(p, off, 64);
    if (sub == 0) out[e] = p;
}

extern "C" void kernel_launch(void* const* d_in, const int* in_sizes, int n_in,
                              void* d_out, int out_size, void* d_ws, size_t ws_size,
                              hipStream_t stream)
{
    const float* x      = (const float*)d_in[0];
    const int*   ei     = (const int*)d_in[1];
    const int*   eli    = (const int*)d_in[2];
    const float* Wg     = (const float*)d_in[3];
    const float* att_s  = (const float*)d_in[4];
    const float* att_d  = (const float*)d_in[5];
    const float* bg     = (const float*)d_in[6];
    const float* W1l    = (const float*)d_in[7];
    const float* W1r    = (const float*)d_in[8];
    const float* b1     = (const float*)d_in[9];
    const float* W2l    = (const float*)d_in[10];
    const float* W2r    = (const float*)d_in[11];
    const float* b2     = (const float*)d_in[12];
    const float* alpha  = (const float*)d_in[13];

    const int N  = in_sizes[0] / 11;
    const int E  = in_sizes[1] / 2;
    const int EL = in_sizes[2] / 2;
    const int NBK = (N + 127) >> 7;
    const int M   = NBK * NCHUNK;
    const int CSRSZ = E + 384 * NBK;

    const int* src = ei;
    const int* dst = ei + E;

    // workspace layout: fp16 node tables (each row 128 B, 16B-aligned), then fp32/int.
    _Float16* Hf  = (_Float16*)d_ws;                   // (N+1)*64  (sentinel row N = 0)
    _Float16* HG  = Hf + (size_t)(N + 1) * 64;         // (N+1)*64  GAT output (+sentinel)
    _Float16* H1  = HG + (size_t)(N + 1) * 64;         // (N+1)*64  layer-1 output (+sentinel)
    _Float16* oD  = H1 + (size_t)(N + 1) * 64;         // N*64  fp16 output accumulator
    _Float16* wf  = oD + (size_t)N * 64;               // 4 x 8192 weight fragments
    _Float16* W1hi = wf;
    _Float16* W1lo = wf + 8192;
    _Float16* W2hi = wf + 16384;
    _Float16* W2lo = wf + 24576;
    float* wsm     = (float*)(wf + 32768);             // 4
    float* a_src   = wsm + 4;                          // N+1
    float* a_dst   = a_src + (N + 1);                  // N
    int*   cnt     = (int*)(a_dst + N);                // N
    int*   rowstart= cnt + N;                          // N
    int*   hist    = rowstart + M ? rowstart + N : rowstart + N; // N (keep simple)
    int*   rstart  = hist + M;                         // M
    int*   bsum    = rstart + M;                       // 256
    int*   csr     = bsum + 256;                       // CSRSZ
    unsigned* ebuf = (unsigned*)H1;                    // E uints; dead before fused layer 1
                                                       // (H1 row N at byte N*128 > E*4, so
                                                       //  sentinel zeroing doesn't clash)

    gat_input_kernel<<<(N + 3) / 4, 256, 0, stream>>>(x, Wg, att_s, att_d, Hf, a_src, a_dst, N,
                                                      W1l, W1r, W2l, W2r,
                                                      W1hi, W1lo, W2hi, W2lo, alpha, wsm,
                                                      HG, H1);

    edge_hist_kernel<<<NCHUNK, 1024, 0, stream>>>(dst, hist, E, NBK);
    int NB = (M + 1023) / 1024;
    scan_reduce_kernel<<<NB, 256, 0, stream>>>(hist, bsum, M);
    scan_apply_kernel<<<NB, 256, 0, stream>>>(hist, bsum, rstart, M, NB);
    edge_scatter_kernel<<<NCHUNK, 1024, 0, stream>>>(src, dst, rstart, ebuf, E, NBK);
    bucket_build_kernel<<<NBK, 256, 0, stream>>>(ebuf, rstart, cnt, rowstart, csr, E, N, NBK);

    gat_gather_kernel<<<(N + 31) / 32, 256, 0, stream>>>(Hf, a_src, a_dst, bg,
                                                         rowstart, cnt, csr, wsm, HG, oD, N);

    sage_fused_kernel<<<(N + 63) / 64, 256, 0, stream>>>(HG, W1hi, W1lo, b1,
                                                         rowstart, cnt, csr, wsm, 2, H1, oD, N);

    sage_fused_kernel<<<(N + 63) / 64, 256, 0, stream>>>(H1, W2hi, W2lo, b2,
                                                         rowstart, cnt, csr, wsm, 3, nullptr, oD, N);

    link_pred_kernel<<<(EL + 31) / 32, 256, 0, stream>>>(eli, oD, (float*)d_out, EL);
}